// Round 13
// baseline (221.632 us; speedup 1.0000x reference)
//
#include <hip/hip_runtime.h>
#include <hip/hip_fp16.h>

#define B_ 1024
#define L_ 1024
#define NCAT_ 20
#define NNUM_ 10
#define E_ 32
#define A_ 128
#define H_ 256
#define TOPK_ 30
#define INV_SQRT_A 0.08838834764831845f

__device__ __forceinline__ void fma4(float4& a, float s, const float4 w) {
    a.x += s * w.x; a.y += s * w.y; a.z += s * w.z; a.w += s * w.w;
}
__device__ __forceinline__ float4 ldh4(const __half* p) {
    float2 rw = *(const float2*)p;
    const __half2* h = (const __half2*)&rw;
    float2 a = __half22float2(h[0]);
    float2 b = __half22float2(h[1]);
    return make_float4(a.x, a.y, b.x, b.y);
}
__device__ __forceinline__ void ldh24(const __half2* p, float4& w1, float4& w2) {
    float4 rw = *(const float4*)p;
    const __half2* h = (const __half2*)&rw;
    float2 f0 = __half22float2(h[0]), f1 = __half22float2(h[1]);
    float2 f2 = __half22float2(h[2]), f3 = __half22float2(h[3]);
    w1 = make_float4(f0.x, f1.x, f2.x, f3.x);
    w2 = make_float4(f0.y, f1.y, f2.y, f3.y);
}
// monotonic float<->u32 (roundtrip exact)
__device__ __forceinline__ unsigned sortable(float f) {
    unsigned u = __float_as_uint(f);
    return (u & 0x80000000u) ? ~u : (u | 0x80000000u);
}
__device__ __forceinline__ float unsortable(unsigned s) {
    unsigned u = (s & 0x80000000u) ? (s ^ 0x80000000u) : ~s;
    return __uint_as_float(u);
}

// ---------------------------------------------------------------------------
// K1: multi-role fused kernel (grid 1356 x 256) — unchanged from R12 (proven).
// ---------------------------------------------------------------------------
#define K1_GRID 1356
__global__ __launch_bounds__(256) void fused_prep_kernel(
    const int* __restrict__ cats, const float* __restrict__ nums,
    const int* __restrict__ tgt_ids, const float* __restrict__ cat_emb,
    const float* __restrict__ Wnum, const float* __restrict__ bnum,
    const float* __restrict__ Wq, const float* __restrict__ Wk,
    const float* __restrict__ Wv, const float* __restrict__ Wo,
    const float* __restrict__ Wpool, const float* __restrict__ bpool,
    const float* __restrict__ seq_emb, const float* __restrict__ Wmlp,
    const float* __restrict__ q1W1, const float* __restrict__ q1W2,
    const float* __restrict__ q2W1, const float* __restrict__ q2W2,
    const float* __restrict__ q1Wp, const float* __restrict__ q2Wp,
    float* __restrict__ p_out, float* __restrict__ fused, float* __restrict__ M,
    __half2* __restrict__ seq_h2, __half2* __restrict__ Wmlp_h2,
    __half2* __restrict__ W12_1, __half2* __restrict__ W12_2,
    __half2* __restrict__ Wp1_h2, __half2* __restrict__ Wp2_h2)
{
    const int blk = blockIdx.x;
    const int t = threadIdx.x;

    if (blk < 256) {
        __shared__ float ce[4][NCAT_ * E_];
        __shared__ float tg[4][E_];
        __shared__ float nm[4][NNUM_];
        __shared__ float qs[4][A_];
        __shared__ float part[8][4][E_];
        const int r0 = blk * 4;

        for (int idx = t; idx < 640; idx += 256) {
            const int q = idx >> 3, f4 = idx & 7;
            const int row = q / 20, cat = q % 20;
            const int tok = cats[(r0 + row) * NCAT_ + cat];
            ((float4*)&ce[row][cat * 32])[f4] =
                ((const float4*)(cat_emb + (size_t)tok * 32))[f4];
        }
        if (t < 32) {
            const int row = t >> 3, f4 = t & 7;
            const int tok = tgt_ids[r0 + row];
            ((float4*)&tg[row][0])[f4] =
                ((const float4*)(cat_emb + (size_t)tok * 32))[f4];
        }
        if (t >= 64 && t < 104) {
            const int x = t - 64;
            nm[x / 10][x % 10] = nums[(r0 + x / 10) * NNUM_ + x % 10];
        }
        __syncthreads();

        {
            const int w = t >> 6, lane = t & 63;
            float q0 = 0.f, q1 = 0.f;
#pragma unroll
            for (int e = 0; e < E_; ++e) {
                float te = tg[w][e];
                q0 += te * Wq[e * A_ + lane];
                q1 += te * Wq[e * A_ + lane + 64];
            }
            qs[w][lane] = q0; qs[w][lane + 64] = q1;
        }

        {
            const int iseg = t >> 5;
            const int row = (t >> 3) & 3;
            const int c0 = (t & 7) * 4;
            float4 acc = make_float4(0.f, 0.f, 0.f, 0.f);
            const int i0 = iseg * 80;
            for (int i = i0; i < i0 + 80; ++i) {
                float4 wv = *(const float4*)(Wpool + i * 32 + c0);
                fma4(acc, ce[row][i], wv);
            }
            *(float4*)&part[iseg][row][c0] = acc;
        }
        __syncthreads();

        if (t < 128) {
            const int row = t >> 5, c = t & 31;
            const int b = r0 + row;
            float s = bpool[c];
#pragma unroll
            for (int g = 0; g < 8; ++g) s += part[g][row][c];
            fused[b * 128 + 64 + c] = s;
            fused[b * 128 + c] = tg[row][c];

            float ne = bnum[c];
#pragma unroll
            for (int n = 0; n < NNUM_; ++n) ne += nm[row][n] * Wnum[n * 32 + c];
            fused[b * 128 + 96 + c] = ne;

            float pv = 0.f;
#pragma unroll 8
            for (int a = 0; a < A_; ++a) pv += Wk[c * A_ + a] * qs[row][a];
            p_out[b * 32 + c] = pv;
        }
        return;
    }

    if (blk < 1280) {
        int x = (blk - 256) * 256 + t;
        for (; x < 800016; x += 1024 * 256) {
            float2 v = ((const float2*)seq_emb)[x];
            seq_h2[x] = __float22half2_rn(v);
        }
        return;
    }

    if (blk < 1284) {
        const int o = (blk - 1280) * 256 + t;
        const int j = o >> 5, e = o & 31;
        float sm = 0.f;
#pragma unroll 8
        for (int a = 0; a < A_; ++a) sm += Wv[j * A_ + a] * Wo[a * E_ + e];
        M[o] = sm;
        return;
    }

    if (blk < 1348) {
        int x = (blk - 1284) * 256 + t;
        for (; x < 65536; x += 64 * 256) {
            W12_1[x] = __float22half2_rn(make_float2(q1W1[x], q1W2[x]));
            W12_2[x] = __float22half2_rn(make_float2(q2W1[x], q2W2[x]));
        }
        return;
    }

    {
        int x = (blk - 1348) * 256 + t;
        for (; x < 16384; x += 8 * 256)
            Wmlp_h2[x] = __float22half2_rn(((const float2*)Wmlp)[x]);
        x = (blk - 1348) * 256 + t;
        for (; x < 32768; x += 8 * 256) {
            Wp1_h2[x] = __float22half2_rn(((const float2*)q1Wp)[x]);
            Wp2_h2[x] = __float22half2_rn(((const float2*)q2Wp)[x]);
        }
    }
}

// ---------------------------------------------------------------------------
// K2: score + top-30 + softmax + interest.  1024 blocks x 512 threads —
// unchanged from R12 (proven).
// ---------------------------------------------------------------------------
__global__ __launch_bounds__(512) void score_topk_kernel(
    const int* __restrict__ seqs, const __half* __restrict__ seq_h,
    const float* __restrict__ seq_emb, const float* __restrict__ p,
    const float* __restrict__ M, const float* __restrict__ bo,
    float* __restrict__ fused)
{
    const int b = blockIdx.x;
    const int t = threadIdx.x;

    __shared__ float sc[L_];
    __shared__ float ps[E_];
    __shared__ float sw[TOPK_];
    __shared__ int   stok[TOPK_];

    if (t < E_) ps[t] = p[b * E_ + t];
    __syncthreads();

    {
        const int tok1 = seqs[b * L_ + t];
        const int tok2 = seqs[b * L_ + t + 512];
        float4 buf[2][4];
        const float4* r1 = (const float4*)(seq_h + (size_t)tok1 * 32);
        const float4* r2 = (const float4*)(seq_h + (size_t)tok2 * 32);
#pragma unroll
        for (int i = 0; i < 4; ++i) buf[0][i] = r1[i];
#pragma unroll
        for (int i = 0; i < 4; ++i) buf[1][i] = r2[i];

        float acc0 = 0.f, acc1 = 0.f;
#pragma unroll
        for (int i = 0; i < 4; ++i) {
            const __half2* h1 = (const __half2*)&buf[0][i];
            const __half2* h2 = (const __half2*)&buf[1][i];
#pragma unroll
            for (int u = 0; u < 4; ++u) {
                float2 f1 = __half22float2(h1[u]);
                float2 f2 = __half22float2(h2[u]);
                acc0 += f1.x * ps[i * 8 + 2 * u] + f1.y * ps[i * 8 + 2 * u + 1];
                acc1 += f2.x * ps[i * 8 + 2 * u] + f2.y * ps[i * 8 + 2 * u + 1];
            }
        }
        sc[t] = acc0 * INV_SQRT_A;
        sc[t + 512] = acc1 * INV_SQRT_A;
    }
    __syncthreads();

    if (t >= 64) return;   // wave 0 only from here
    const int lane = t;

    unsigned long long key[16];
#pragma unroll
    for (int j = 0; j < 16; ++j) {
        const int l = j * 64 + lane;
        key[j] = ((unsigned long long)sortable(sc[l]) << 10)
               | (unsigned)(1023 - l);
    }
#pragma unroll
    for (int a = 0; a < 15; ++a)
#pragma unroll
        for (int j = 0; j < 15 - a; ++j) {
            const bool swp = key[j] < key[j + 1];
            const unsigned long long hi = swp ? key[j + 1] : key[j];
            const unsigned long long lo = swp ? key[j] : key[j + 1];
            key[j] = hi; key[j + 1] = lo;
        }

    float myv = -1e30f; int myl = 0;
    unsigned long long front = key[0];
    for (int k = 0; k < TOPK_; ++k) {
        unsigned long long wk = front;
#pragma unroll
        for (int off = 32; off > 0; off >>= 1) {
            unsigned long long o = __shfl_xor(wk, off);
            if (o > wk) wk = o;
        }
        if (lane == k) {
            myv = unsortable((unsigned)(wk >> 10));
            myl = 1023 - (int)(wk & 1023);
        }
        if (front == wk) {
#pragma unroll
            for (int j = 0; j < 15; ++j) key[j] = key[j + 1];
            key[15] = 0ULL;
            front = key[0];
        }
    }

    float m = myv;
#pragma unroll
    for (int off = 32; off > 0; off >>= 1) m = fmaxf(m, __shfl_xor(m, off));
    float e = (lane < TOPK_) ? expf(myv - m) : 0.f;
    float s = e;
#pragma unroll
    for (int off = 32; off > 0; off >>= 1) s += __shfl_xor(s, off);
    if (lane < TOPK_) {
        sw[lane]   = e / s;
        stok[lane] = seqs[b * L_ + myl];
    }

    if (lane < E_) {
        float acc = 0.f;
#pragma unroll
        for (int k = 0; k < TOPK_; ++k)
            acc += sw[k] * seq_emb[(size_t)stok[k] * 32 + lane];
        sc[lane] = acc;
    }
    if (lane < E_) {
        float acc = bo[lane];
#pragma unroll
        for (int j = 0; j < E_; ++j) acc += sc[j] * M[j * E_ + lane];
        fused[b * 128 + 32 + lane] = acc;
    }
}

// ---------------------------------------------------------------------------
// K3: MLP chain.  256 blocks x 1024 threads, RM=4, 16 i-segments.
// 2x waves/CU vs R12 (8->16); per-thread serial work halved; barriers and L2
// weight latency hide behind the extra parallelism.  part = 64 KB (~74 total).
// ---------------------------------------------------------------------------
#define RM 4
#define NSEG 16
__global__ __launch_bounds__(1024) void mlp_kernel(
    const float* __restrict__ fused,
    const __half* __restrict__ Wmlp_h, const float* __restrict__ bmlp,
    const __half2* __restrict__ W12_1, const float* __restrict__ b11,
    const float* __restrict__ b12, const __half* __restrict__ Wp1_h,
    const float* __restrict__ b1p,
    const __half2* __restrict__ W12_2, const float* __restrict__ b21,
    const float* __restrict__ b22, const __half* __restrict__ Wp2_h,
    const float* __restrict__ b2p,
    const float* __restrict__ Wout, const float* __restrict__ bout,
    float* __restrict__ out)
{
    const int b0 = blockIdx.x * RM;
    const int tid = threadIdx.x;
    const int cg = tid & 63;          // 64 col groups x 4 cols
    const int iseg = tid >> 6;        // 0..15
    const int c0 = cg * 4;

    __shared__ float xs[RM][128];
    __shared__ float hs[RM][H_];
    __shared__ float ts[RM][H_];
    __shared__ float part[NSEG][RM][H_];   // 64 KB
    __shared__ float red[16];

    for (int i = tid; i < RM * 128; i += 1024) xs[i >> 7][i & 127] = fused[b0 * 128 + i];
    __syncthreads();

    // ---- stage 1: hs = relu(xs @ Wmlp + bmlp); K=128 -> 8 i's per segment
    {
        float4 acc[RM];
#pragma unroll
        for (int r = 0; r < RM; ++r) acc[r] = make_float4(0.f, 0.f, 0.f, 0.f);
        const int i0 = iseg * 8;
#pragma unroll
        for (int iq = 0; iq < 2; ++iq) {
            const int i = i0 + iq * 4;
            float4 w[4], xv[RM];
#pragma unroll
            for (int u = 0; u < 4; ++u) w[u] = ldh4(Wmlp_h + (i + u) * H_ + c0);
#pragma unroll
            for (int r = 0; r < RM; ++r) xv[r] = *(const float4*)(&xs[r][i]);
#pragma unroll
            for (int r = 0; r < RM; ++r) {
                fma4(acc[r], xv[r].x, w[0]); fma4(acc[r], xv[r].y, w[1]);
                fma4(acc[r], xv[r].z, w[2]); fma4(acc[r], xv[r].w, w[3]);
            }
        }
#pragma unroll
        for (int r = 0; r < RM; ++r) *(float4*)&part[iseg][r][c0] = acc[r];
    }
    __syncthreads();
    {
        const int r = tid >> 8, c = tid & 255;   // one output per thread
        float s = bmlp[c];
#pragma unroll
        for (int sg = 0; sg < NSEG; ++sg) s += part[sg][r][c];
        hs[r][c] = fmaxf(s, 0.f);
    }
    __syncthreads();

    const __half2* W12s[2] = { W12_1, W12_2 };
    const float* b1s[2] = { b11, b21 }; const float* b2s[2] = { b12, b22 };
    const __half* Wps[2] = { Wp1_h, Wp2_h }; const float* bps[2] = { b1p, b2p };

    for (int q = 0; q < 2; ++q) {
        const __half2* __restrict__ W12 = W12s[q];
        const __half*  __restrict__ Wp  = Wps[q];
        float4 a1[RM], a2[RM];
        {
#pragma unroll
            for (int r = 0; r < RM; ++r) {
                a1[r] = make_float4(0.f, 0.f, 0.f, 0.f);
                a2[r] = make_float4(0.f, 0.f, 0.f, 0.f);
            }
            const int i0 = iseg * 16;   // K=256 -> 16 i's per segment
#pragma unroll
            for (int iq = 0; iq < 4; ++iq) {
                const int i = i0 + iq * 4;
                float4 w1[4], w2[4], hv[RM];
#pragma unroll
                for (int u = 0; u < 4; ++u) ldh24(W12 + (i + u) * H_ + c0, w1[u], w2[u]);
#pragma unroll
                for (int r = 0; r < RM; ++r) hv[r] = *(const float4*)(&hs[r][i]);
#pragma unroll
                for (int r = 0; r < RM; ++r) {
                    fma4(a1[r], hv[r].x, w1[0]); fma4(a1[r], hv[r].y, w1[1]);
                    fma4(a1[r], hv[r].z, w1[2]); fma4(a1[r], hv[r].w, w1[3]);
                    fma4(a2[r], hv[r].x, w2[0]); fma4(a2[r], hv[r].y, w2[1]);
                    fma4(a2[r], hv[r].z, w2[2]); fma4(a2[r], hv[r].w, w2[3]);
                }
            }
        }
        // t1 via part (a2 stays in registers across the barriers)
#pragma unroll
        for (int r = 0; r < RM; ++r) *(float4*)&part[iseg][r][c0] = a1[r];
        __syncthreads();
        {
            const int r = tid >> 8, c = tid & 255;
            float t1 = b1s[q][c];
#pragma unroll
            for (int sg = 0; sg < NSEG; ++sg) t1 += part[sg][r][c];
            ts[r][c] = t1;
        }
        __syncthreads();
        // t2 via part, multiply into ts
#pragma unroll
        for (int r = 0; r < RM; ++r) *(float4*)&part[iseg][r][c0] = a2[r];
        __syncthreads();
        {
            const int r = tid >> 8, c = tid & 255;
            float t2 = b2s[q][c];
#pragma unroll
            for (int sg = 0; sg < NSEG; ++sg) t2 += part[sg][r][c];
            ts[r][c] = ts[r][c] * t2;
        }
        __syncthreads();

        // projection: hs += ts @ Wp + bp
        {
            float4 ap[RM];
#pragma unroll
            for (int r = 0; r < RM; ++r) ap[r] = make_float4(0.f, 0.f, 0.f, 0.f);
            const int i0 = iseg * 16;
#pragma unroll
            for (int iq = 0; iq < 4; ++iq) {
                const int i = i0 + iq * 4;
                float4 w[4], tv[RM];
#pragma unroll
                for (int u = 0; u < 4; ++u) w[u] = ldh4(Wp + (i + u) * H_ + c0);
#pragma unroll
                for (int r = 0; r < RM; ++r) tv[r] = *(const float4*)(&ts[r][i]);
#pragma unroll
                for (int r = 0; r < RM; ++r) {
                    fma4(ap[r], tv[r].x, w[0]); fma4(ap[r], tv[r].y, w[1]);
                    fma4(ap[r], tv[r].z, w[2]); fma4(ap[r], tv[r].w, w[3]);
                }
            }
#pragma unroll
            for (int r = 0; r < RM; ++r) *(float4*)&part[iseg][r][c0] = ap[r];
        }
        __syncthreads();
        {
            const int r = tid >> 8, c = tid & 255;
            float s = bps[q][c];
#pragma unroll
            for (int sg = 0; sg < NSEG; ++sg) s += part[sg][r][c];
            hs[r][c] += s;
        }
        __syncthreads();
    }

    // ---- out[r] = hs[r].Wout + bout  (256 thr/row = 4 waves/row)
    {
        const int r = tid >> 8, jj = tid & 255;
        float sum = hs[r][jj] * Wout[jj];
#pragma unroll
        for (int off = 32; off > 0; off >>= 1) sum += __shfl_down(sum, off);
        if ((tid & 63) == 0) red[tid >> 6] = sum;
        __syncthreads();
        if (tid < RM)
            out[b0 + tid] = red[4 * tid] + red[4 * tid + 1]
                          + red[4 * tid + 2] + red[4 * tid + 3] + bout[0];
    }
}

// ---------------------------------------------------------------------------
extern "C" void kernel_launch(void* const* d_in, const int* in_sizes, int n_in,
                              void* d_out, int out_size, void* d_ws, size_t ws_size,
                              hipStream_t stream) {
    const int*   cats    = (const int*)d_in[0];
    const float* nums    = (const float*)d_in[1];
    const int*   seqs    = (const int*)d_in[2];
    const int*   tgt_ids = (const int*)d_in[3];
    const float* cat_emb = (const float*)d_in[4];
    const float* seq_emb = (const float*)d_in[5];
    const float* Wnum    = (const float*)d_in[6];
    const float* bnum    = (const float*)d_in[7];
    const float* Wq      = (const float*)d_in[8];
    const float* Wk      = (const float*)d_in[9];
    const float* Wv      = (const float*)d_in[10];
    const float* Wo      = (const float*)d_in[11];
    const float* bo      = (const float*)d_in[12];
    const float* Wpool   = (const float*)d_in[13];
    const float* bpool   = (const float*)d_in[14];
    const float* Wmlp    = (const float*)d_in[15];
    const float* bmlp    = (const float*)d_in[16];
    const float* q1_W1   = (const float*)d_in[17];
    const float* q1_b1   = (const float*)d_in[18];
    const float* q1_W2   = (const float*)d_in[19];
    const float* q1_b2   = (const float*)d_in[20];
    const float* q1_Wp   = (const float*)d_in[21];
    const float* q1_bp   = (const float*)d_in[22];
    const float* q2_W1   = (const float*)d_in[23];
    const float* q2_b1   = (const float*)d_in[24];
    const float* q2_W2   = (const float*)d_in[25];
    const float* q2_b2   = (const float*)d_in[26];
    const float* q2_Wp   = (const float*)d_in[27];
    const float* q2_bp   = (const float*)d_in[28];
    const float* Wout    = (const float*)d_in[29];
    const float* bout    = (const float*)d_in[30];

    // Workspace layout (float-slot offsets); one half2 == one 4 B slot.
    // seq_h2 needs 800064 slots; Wp buffers need 32768 slots EACH (full Wp).
    float* ws = (float*)d_ws;
    float*   p       = ws;                         //      0 .. 32768
    float*   fused   = ws + 32768;                 //  32768 .. 163840
    float*   M       = ws + 163840;                // 163840 .. 164864
    __half2* seq_h2  = (__half2*)(ws + 164864);    // 164864 .. 964928 (800064)
    __half2* Wmlp_h2 = (__half2*)(ws + 964928);    // 964928 .. 981312
    __half2* W12_1   = (__half2*)(ws + 981312);    // 981312 .. 1046848
    __half2* W12_2   = (__half2*)(ws + 1046848);   // 1046848 .. 1112384
    __half2* Wp1_h2  = (__half2*)(ws + 1112384);   // 1112384 .. 1145152 (32768)
    __half2* Wp2_h2  = (__half2*)(ws + 1145152);   // 1145152 .. 1177920 (32768)

    float* out = (float*)d_out;

    fused_prep_kernel<<<K1_GRID, 256, 0, stream>>>(
        cats, nums, tgt_ids, cat_emb, Wnum, bnum, Wq, Wk, Wv, Wo,
        Wpool, bpool, seq_emb, Wmlp,
        q1_W1, q1_W2, q2_W1, q2_W2, q1_Wp, q2_Wp,
        p, fused, M, seq_h2, Wmlp_h2, W12_1, W12_2, Wp1_h2, Wp2_h2);

    score_topk_kernel<<<B_, 512, 0, stream>>>(
        seqs, (const __half*)seq_h2, seq_emb, p, M, bo, fused);

    mlp_kernel<<<B_ / RM, 1024, 0, stream>>>(
        fused, (const __half*)Wmlp_h2, bmlp,
        W12_1, q1_b1, q1_b2, (const __half*)Wp1_h2, q1_bp,
        W12_2, q2_b1, q2_b2, (const __half*)Wp2_h2, q2_bp,
        Wout, bout, out);
}

// Round 14
// 179.457 us; speedup vs baseline: 1.2350x; 1.2350x over previous
//
#include <hip/hip_runtime.h>
#include <hip/hip_fp16.h>

#define B_ 1024
#define L_ 1024
#define NCAT_ 20
#define NNUM_ 10
#define E_ 32
#define A_ 128
#define H_ 256
#define TOPK_ 30
#define INV_SQRT_A 0.08838834764831845f

__device__ __forceinline__ void fma4(float4& a, float s, const float4 w) {
    a.x += s * w.x; a.y += s * w.y; a.z += s * w.z; a.w += s * w.w;
}
__device__ __forceinline__ float4 ldh4(const __half* p) {
    float2 rw = *(const float2*)p;
    const __half2* h = (const __half2*)&rw;
    float2 a = __half22float2(h[0]);
    float2 b = __half22float2(h[1]);
    return make_float4(a.x, a.y, b.x, b.y);
}
__device__ __forceinline__ void ldh24(const __half2* p, float4& w1, float4& w2) {
    float4 rw = *(const float4*)p;
    const __half2* h = (const __half2*)&rw;
    float2 f0 = __half22float2(h[0]), f1 = __half22float2(h[1]);
    float2 f2 = __half22float2(h[2]), f3 = __half22float2(h[3]);
    w1 = make_float4(f0.x, f1.x, f2.x, f3.x);
    w2 = make_float4(f0.y, f1.y, f2.y, f3.y);
}
// monotonic float<->u32 (roundtrip exact)
__device__ __forceinline__ unsigned sortable(float f) {
    unsigned u = __float_as_uint(f);
    return (u & 0x80000000u) ? ~u : (u | 0x80000000u);
}
__device__ __forceinline__ float unsortable(unsigned s) {
    unsigned u = (s & 0x80000000u) ? (s ^ 0x80000000u) : ~s;
    return __uint_as_float(u);
}

// ---------------------------------------------------------------------------
// K1: multi-role fused kernel (grid 1356 x 256) — R10-proven.
//   blocks [0,256)     : prep, 4 rows each
//   blocks [256,1280)  : seq_emb -> fp16 convert
//   blocks [1280,1284) : M = Wv@Wo
//   blocks [1284,1348) : pack half2(W1,W2) for both qnn
//   blocks [1348,1356) : Wmlp, Wp1, Wp2 -> fp16 (FULL 32768-slot Wp convert)
// ---------------------------------------------------------------------------
#define K1_GRID 1356
__global__ __launch_bounds__(256) void fused_prep_kernel(
    const int* __restrict__ cats, const float* __restrict__ nums,
    const int* __restrict__ tgt_ids, const float* __restrict__ cat_emb,
    const float* __restrict__ Wnum, const float* __restrict__ bnum,
    const float* __restrict__ Wq, const float* __restrict__ Wk,
    const float* __restrict__ Wv, const float* __restrict__ Wo,
    const float* __restrict__ Wpool, const float* __restrict__ bpool,
    const float* __restrict__ seq_emb, const float* __restrict__ Wmlp,
    const float* __restrict__ q1W1, const float* __restrict__ q1W2,
    const float* __restrict__ q2W1, const float* __restrict__ q2W2,
    const float* __restrict__ q1Wp, const float* __restrict__ q2Wp,
    float* __restrict__ p_out, float* __restrict__ fused, float* __restrict__ M,
    __half2* __restrict__ seq_h2, __half2* __restrict__ Wmlp_h2,
    __half2* __restrict__ W12_1, __half2* __restrict__ W12_2,
    __half2* __restrict__ Wp1_h2, __half2* __restrict__ Wp2_h2)
{
    const int blk = blockIdx.x;
    const int t = threadIdx.x;

    if (blk < 256) {
        __shared__ float ce[4][NCAT_ * E_];
        __shared__ float tg[4][E_];
        __shared__ float nm[4][NNUM_];
        __shared__ float qs[4][A_];
        __shared__ float part[8][4][E_];
        const int r0 = blk * 4;

        for (int idx = t; idx < 640; idx += 256) {
            const int q = idx >> 3, f4 = idx & 7;
            const int row = q / 20, cat = q % 20;
            const int tok = cats[(r0 + row) * NCAT_ + cat];
            ((float4*)&ce[row][cat * 32])[f4] =
                ((const float4*)(cat_emb + (size_t)tok * 32))[f4];
        }
        if (t < 32) {
            const int row = t >> 3, f4 = t & 7;
            const int tok = tgt_ids[r0 + row];
            ((float4*)&tg[row][0])[f4] =
                ((const float4*)(cat_emb + (size_t)tok * 32))[f4];
        }
        if (t >= 64 && t < 104) {
            const int x = t - 64;
            nm[x / 10][x % 10] = nums[(r0 + x / 10) * NNUM_ + x % 10];
        }
        __syncthreads();

        {
            const int w = t >> 6, lane = t & 63;
            float q0 = 0.f, q1 = 0.f;
#pragma unroll
            for (int e = 0; e < E_; ++e) {
                float te = tg[w][e];
                q0 += te * Wq[e * A_ + lane];
                q1 += te * Wq[e * A_ + lane + 64];
            }
            qs[w][lane] = q0; qs[w][lane + 64] = q1;
        }

        {
            const int iseg = t >> 5;
            const int row = (t >> 3) & 3;
            const int c0 = (t & 7) * 4;
            float4 acc = make_float4(0.f, 0.f, 0.f, 0.f);
            const int i0 = iseg * 80;
            for (int i = i0; i < i0 + 80; ++i) {
                float4 wv = *(const float4*)(Wpool + i * 32 + c0);
                fma4(acc, ce[row][i], wv);
            }
            *(float4*)&part[iseg][row][c0] = acc;
        }
        __syncthreads();

        if (t < 128) {
            const int row = t >> 5, c = t & 31;
            const int b = r0 + row;
            float s = bpool[c];
#pragma unroll
            for (int g = 0; g < 8; ++g) s += part[g][row][c];
            fused[b * 128 + 64 + c] = s;
            fused[b * 128 + c] = tg[row][c];

            float ne = bnum[c];
#pragma unroll
            for (int n = 0; n < NNUM_; ++n) ne += nm[row][n] * Wnum[n * 32 + c];
            fused[b * 128 + 96 + c] = ne;

            float pv = 0.f;
#pragma unroll 8
            for (int a = 0; a < A_; ++a) pv += Wk[c * A_ + a] * qs[row][a];
            p_out[b * 32 + c] = pv;
        }
        return;
    }

    if (blk < 1280) {
        int x = (blk - 256) * 256 + t;
        for (; x < 800016; x += 1024 * 256) {
            float2 v = ((const float2*)seq_emb)[x];
            seq_h2[x] = __float22half2_rn(v);
        }
        return;
    }

    if (blk < 1284) {
        const int o = (blk - 1280) * 256 + t;
        const int j = o >> 5, e = o & 31;
        float sm = 0.f;
#pragma unroll 8
        for (int a = 0; a < A_; ++a) sm += Wv[j * A_ + a] * Wo[a * E_ + e];
        M[o] = sm;
        return;
    }

    if (blk < 1348) {
        int x = (blk - 1284) * 256 + t;
        for (; x < 65536; x += 64 * 256) {
            W12_1[x] = __float22half2_rn(make_float2(q1W1[x], q1W2[x]));
            W12_2[x] = __float22half2_rn(make_float2(q2W1[x], q2W2[x]));
        }
        return;
    }

    {
        int x = (blk - 1348) * 256 + t;
        for (; x < 16384; x += 8 * 256)
            Wmlp_h2[x] = __float22half2_rn(((const float2*)Wmlp)[x]);
        // Wp is 256x256 = 32768 float2 — FULL conversion.
        x = (blk - 1348) * 256 + t;
        for (; x < 32768; x += 8 * 256) {
            Wp1_h2[x] = __float22half2_rn(((const float2*)q1Wp)[x]);
            Wp2_h2[x] = __float22half2_rn(((const float2*)q2Wp)[x]);
        }
    }
}

// ---------------------------------------------------------------------------
// K2: score + top-30 + softmax + interest + MLP, fused.  256 blocks x 512.
// R10-proven (179.4 µs): single 32 KB part buffer, a2 held in registers
// across barriers; LDS ~60 KB.
// ---------------------------------------------------------------------------
#define RM 4
__global__ __launch_bounds__(512) void score_mlp_kernel(
    const int* __restrict__ seqs, const __half* __restrict__ seq_h,
    const float* __restrict__ seq_emb, const float* __restrict__ p,
    const float* __restrict__ M, const float* __restrict__ bo,
    const float* __restrict__ fused,
    const __half* __restrict__ Wmlp_h, const float* __restrict__ bmlp,
    const __half2* __restrict__ W12_1, const float* __restrict__ b11,
    const float* __restrict__ b12, const __half* __restrict__ Wp1_h,
    const float* __restrict__ b1p,
    const __half2* __restrict__ W12_2, const float* __restrict__ b21,
    const float* __restrict__ b22, const __half* __restrict__ Wp2_h,
    const float* __restrict__ b2p,
    const float* __restrict__ Wout, const float* __restrict__ bout,
    float* __restrict__ out)
{
    const int b0 = blockIdx.x * RM;
    const int tid = threadIdx.x;

    __shared__ float sc[RM][L_];        // 16 KB (score rows; reused as ebar)
    __shared__ float ps[RM][E_];
    __shared__ float sw[RM][32];
    __shared__ int   stok[RM][32];
    __shared__ float xs[RM][128];
    __shared__ float hs[RM][H_];
    __shared__ float ts[RM][H_];
    __shared__ float part[8][RM][H_];   // 32 KB single buffer
    __shared__ float red[8];

    if (tid < 128) ps[tid >> 5][tid & 31] = p[(b0 + (tid >> 5)) * 32 + (tid & 31)];
    __syncthreads();

    // ---- Phase A: scores. row = tid>>7, 128 threads/row, 8 tokens/thread
    {
        const int row = tid >> 7;
        const int s = tid & 127;
        const int bb = b0 + row;
#pragma unroll
        for (int jj = 0; jj < 4; ++jj) {
            const int l1 = jj * 256 + s;
            const int l2 = l1 + 128;
            const int tok1 = seqs[bb * L_ + l1];
            const int tok2 = seqs[bb * L_ + l2];
            float4 buf[2][4];
            const float4* r1 = (const float4*)(seq_h + (size_t)tok1 * 32);
            const float4* r2 = (const float4*)(seq_h + (size_t)tok2 * 32);
#pragma unroll
            for (int i = 0; i < 4; ++i) buf[0][i] = r1[i];
#pragma unroll
            for (int i = 0; i < 4; ++i) buf[1][i] = r2[i];

            float acc0 = 0.f, acc1 = 0.f;
#pragma unroll
            for (int i = 0; i < 4; ++i) {
                const __half2* h1 = (const __half2*)&buf[0][i];
                const __half2* h2 = (const __half2*)&buf[1][i];
#pragma unroll
                for (int u = 0; u < 4; ++u) {
                    float2 f1 = __half22float2(h1[u]);
                    float2 f2 = __half22float2(h2[u]);
                    acc0 += f1.x * ps[row][i * 8 + 2 * u] + f1.y * ps[row][i * 8 + 2 * u + 1];
                    acc1 += f2.x * ps[row][i * 8 + 2 * u] + f2.y * ps[row][i * 8 + 2 * u + 1];
                }
            }
            sc[row][l1] = acc0 * INV_SQRT_A;
            sc[row][l2] = acc1 * INV_SQRT_A;
        }
    }
    // xs cols 0-31 and 64-127 from K1's fused (interest cols filled below)
    if (tid < 384) {
        const int r = tid / 96, c0 = tid % 96;
        const int c = (c0 < 32) ? c0 : (c0 + 32);
        xs[r][c] = fused[(b0 + r) * 128 + c];
    }
    __syncthreads();

    // ---- Phase B: selection, one row per wave (waves 0-3).
    if (tid < 256) {
        const int w = tid >> 6;
        const int lane = tid & 63;
        const int bb = b0 + w;

        unsigned long long key[16];
#pragma unroll
        for (int j = 0; j < 16; ++j) {
            const int l = j * 64 + lane;
            key[j] = ((unsigned long long)sortable(sc[w][l]) << 10)
                   | (unsigned)(1023 - l);
        }
#pragma unroll
        for (int a = 0; a < 15; ++a)
#pragma unroll
            for (int j = 0; j < 15 - a; ++j) {
                const bool swp = key[j] < key[j + 1];
                const unsigned long long hi = swp ? key[j + 1] : key[j];
                const unsigned long long lo = swp ? key[j] : key[j + 1];
                key[j] = hi; key[j + 1] = lo;
            }

        float myv = -1e30f; int myl = 0;
        unsigned long long front = key[0];
        for (int k = 0; k < TOPK_; ++k) {
            unsigned long long wk = front;
#pragma unroll
            for (int off = 32; off > 0; off >>= 1) {
                unsigned long long o = __shfl_xor(wk, off);
                if (o > wk) wk = o;
            }
            if (lane == k) {
                myv = unsortable((unsigned)(wk >> 10));
                myl = 1023 - (int)(wk & 1023);
            }
            if (front == wk) {
#pragma unroll
                for (int j = 0; j < 15; ++j) key[j] = key[j + 1];
                key[15] = 0ULL;
                front = key[0];
            }
        }

        float m = myv;
#pragma unroll
        for (int off = 32; off > 0; off >>= 1) m = fmaxf(m, __shfl_xor(m, off));
        float e = (lane < TOPK_) ? expf(myv - m) : 0.f;
        float s = e;
#pragma unroll
        for (int off = 32; off > 0; off >>= 1) s += __shfl_xor(s, off);
        if (lane < TOPK_) {
            sw[w][lane]   = e / s;
            stok[w][lane] = seqs[bb * L_ + myl];
        }

        if (lane < E_) {
            float acc = 0.f;
#pragma unroll
            for (int k = 0; k < TOPK_; ++k)
                acc += sw[w][k] * seq_emb[(size_t)stok[w][k] * 32 + lane];
            sc[w][lane] = acc;   // ebar (sc row free now; same-wave r/w)
        }
        if (lane < E_) {
            float acc = bo[lane];
#pragma unroll
            for (int j = 0; j < E_; ++j) acc += sc[w][j] * M[j * E_ + lane];
            xs[w][32 + lane] = acc;   // interest -> LDS
        }
    }
    __syncthreads();

    // ---- Phase C: MLP, single-buffer part.
    const int cg = tid & 63;
    const int iseg = tid >> 6;
    const int c0 = cg * 4;

    {
        float4 acc[RM];
#pragma unroll
        for (int r = 0; r < RM; ++r) acc[r] = make_float4(0.f, 0.f, 0.f, 0.f);
        const int i0 = iseg * 16;
#pragma unroll
        for (int iq = 0; iq < 4; ++iq) {
            const int i = i0 + iq * 4;
            float4 w[4], xv[RM];
#pragma unroll
            for (int u = 0; u < 4; ++u) w[u] = ldh4(Wmlp_h + (i + u) * H_ + c0);
#pragma unroll
            for (int r = 0; r < RM; ++r) xv[r] = *(const float4*)(&xs[r][i]);
#pragma unroll
            for (int r = 0; r < RM; ++r) {
                fma4(acc[r], xv[r].x, w[0]); fma4(acc[r], xv[r].y, w[1]);
                fma4(acc[r], xv[r].z, w[2]); fma4(acc[r], xv[r].w, w[3]);
            }
        }
#pragma unroll
        for (int r = 0; r < RM; ++r) *(float4*)&part[iseg][r][c0] = acc[r];
    }
    __syncthreads();
    for (int o = tid; o < RM * H_; o += 512) {
        const int r = o >> 8, c = o & 255;
        float s = bmlp[c];
#pragma unroll
        for (int sg = 0; sg < 8; ++sg) s += part[sg][r][c];
        hs[r][c] = fmaxf(s, 0.f);
    }
    __syncthreads();

    const __half2* W12s[2] = { W12_1, W12_2 };
    const float* b1s[2] = { b11, b21 }; const float* b2s[2] = { b12, b22 };
    const __half* Wps[2] = { Wp1_h, Wp2_h }; const float* bps[2] = { b1p, b2p };

    for (int q = 0; q < 2; ++q) {
        const __half2* __restrict__ W12 = W12s[q];
        const __half*  __restrict__ Wp  = Wps[q];
        float4 a1[RM], a2[RM];
        {
#pragma unroll
            for (int r = 0; r < RM; ++r) {
                a1[r] = make_float4(0.f, 0.f, 0.f, 0.f);
                a2[r] = make_float4(0.f, 0.f, 0.f, 0.f);
            }
            const int i0 = iseg * 32;
#pragma unroll 2
            for (int iq = 0; iq < 8; ++iq) {
                const int i = i0 + iq * 4;
                float4 w1[4], w2[4], hv[RM];
#pragma unroll
                for (int u = 0; u < 4; ++u) ldh24(W12 + (i + u) * H_ + c0, w1[u], w2[u]);
#pragma unroll
                for (int r = 0; r < RM; ++r) hv[r] = *(const float4*)(&hs[r][i]);
#pragma unroll
                for (int r = 0; r < RM; ++r) {
                    fma4(a1[r], hv[r].x, w1[0]); fma4(a1[r], hv[r].y, w1[1]);
                    fma4(a1[r], hv[r].z, w1[2]); fma4(a1[r], hv[r].w, w1[3]);
                    fma4(a2[r], hv[r].x, w2[0]); fma4(a2[r], hv[r].y, w2[1]);
                    fma4(a2[r], hv[r].z, w2[2]); fma4(a2[r], hv[r].w, w2[3]);
                }
            }
        }
        // t1 via part (a2 stays in registers across the barriers)
#pragma unroll
        for (int r = 0; r < RM; ++r) *(float4*)&part[iseg][r][c0] = a1[r];
        __syncthreads();
        {
            const float* b1 = b1s[q];
            for (int o = tid; o < RM * H_; o += 512) {
                const int r = o >> 8, c = o & 255;
                float t1 = b1[c];
#pragma unroll
                for (int sg = 0; sg < 8; ++sg) t1 += part[sg][r][c];
                ts[r][c] = t1;
            }
        }
        __syncthreads();
        // t2 via part, multiply into ts
#pragma unroll
        for (int r = 0; r < RM; ++r) *(float4*)&part[iseg][r][c0] = a2[r];
        __syncthreads();
        {
            const float* b2 = b2s[q];
            for (int o = tid; o < RM * H_; o += 512) {
                const int r = o >> 8, c = o & 255;
                float t2 = b2[c];
#pragma unroll
                for (int sg = 0; sg < 8; ++sg) t2 += part[sg][r][c];
                ts[r][c] = ts[r][c] * t2;
            }
        }
        __syncthreads();

        // projection: hs += ts @ Wp + bp
        {
            float4 ap[RM];
#pragma unroll
            for (int r = 0; r < RM; ++r) ap[r] = make_float4(0.f, 0.f, 0.f, 0.f);
            const int i0 = iseg * 32;
#pragma unroll 2
            for (int iq = 0; iq < 8; ++iq) {
                const int i = i0 + iq * 4;
                float4 w[4], tv[RM];
#pragma unroll
                for (int u = 0; u < 4; ++u) w[u] = ldh4(Wp + (i + u) * H_ + c0);
#pragma unroll
                for (int r = 0; r < RM; ++r) tv[r] = *(const float4*)(&ts[r][i]);
#pragma unroll
                for (int r = 0; r < RM; ++r) {
                    fma4(ap[r], tv[r].x, w[0]); fma4(ap[r], tv[r].y, w[1]);
                    fma4(ap[r], tv[r].z, w[2]); fma4(ap[r], tv[r].w, w[3]);
                }
            }
#pragma unroll
            for (int r = 0; r < RM; ++r) *(float4*)&part[iseg][r][c0] = ap[r];
        }
        __syncthreads();
        {
            const float* bp = bps[q];
            for (int o = tid; o < RM * H_; o += 512) {
                const int r = o >> 8, c = o & 255;
                float s = bp[c];
#pragma unroll
                for (int sg = 0; sg < 8; ++sg) s += part[sg][r][c];
                hs[r][c] += s;
            }
        }
        __syncthreads();
    }

    {
        const int r = tid >> 7, jj = tid & 127;
        float sum = hs[r][jj] * Wout[jj] + hs[r][jj + 128] * Wout[jj + 128];
#pragma unroll
        for (int off = 32; off > 0; off >>= 1) sum += __shfl_down(sum, off);
        if ((tid & 63) == 0) red[tid >> 6] = sum;
        __syncthreads();
        if (tid < RM) out[b0 + tid] = red[2 * tid] + red[2 * tid + 1] + bout[0];
    }
}

// ---------------------------------------------------------------------------
extern "C" void kernel_launch(void* const* d_in, const int* in_sizes, int n_in,
                              void* d_out, int out_size, void* d_ws, size_t ws_size,
                              hipStream_t stream) {
    const int*   cats    = (const int*)d_in[0];
    const float* nums    = (const float*)d_in[1];
    const int*   seqs    = (const int*)d_in[2];
    const int*   tgt_ids = (const int*)d_in[3];
    const float* cat_emb = (const float*)d_in[4];
    const float* seq_emb = (const float*)d_in[5];
    const float* Wnum    = (const float*)d_in[6];
    const float* bnum    = (const float*)d_in[7];
    const float* Wq      = (const float*)d_in[8];
    const float* Wk      = (const float*)d_in[9];
    const float* Wv      = (const float*)d_in[10];
    const float* Wo      = (const float*)d_in[11];
    const float* bo      = (const float*)d_in[12];
    const float* Wpool   = (const float*)d_in[13];
    const float* bpool   = (const float*)d_in[14];
    const float* Wmlp    = (const float*)d_in[15];
    const float* bmlp    = (const float*)d_in[16];
    const float* q1_W1   = (const float*)d_in[17];
    const float* q1_b1   = (const float*)d_in[18];
    const float* q1_W2   = (const float*)d_in[19];
    const float* q1_b2   = (const float*)d_in[20];
    const float* q1_Wp   = (const float*)d_in[21];
    const float* q1_bp   = (const float*)d_in[22];
    const float* q2_W1   = (const float*)d_in[23];
    const float* q2_b1   = (const float*)d_in[24];
    const float* q2_W2   = (const float*)d_in[25];
    const float* q2_b2   = (const float*)d_in[26];
    const float* q2_Wp   = (const float*)d_in[27];
    const float* q2_bp   = (const float*)d_in[28];
    const float* Wout    = (const float*)d_in[29];
    const float* bout    = (const float*)d_in[30];

    // Workspace layout (float-slot offsets); one half2 == one 4 B slot.
    // seq_h2 needs 800064 slots; Wp buffers need 32768 slots EACH (full Wp).
    float* ws = (float*)d_ws;
    float*   p       = ws;                         //      0 .. 32768
    float*   fused   = ws + 32768;                 //  32768 .. 163840
    float*   M       = ws + 163840;                // 163840 .. 164864
    __half2* seq_h2  = (__half2*)(ws + 164864);    // 164864 .. 964928 (800064)
    __half2* Wmlp_h2 = (__half2*)(ws + 964928);    // 964928 .. 981312
    __half2* W12_1   = (__half2*)(ws + 981312);    // 981312 .. 1046848
    __half2* W12_2   = (__half2*)(ws + 1046848);   // 1046848 .. 1112384
    __half2* Wp1_h2  = (__half2*)(ws + 1112384);   // 1112384 .. 1145152 (32768)
    __half2* Wp2_h2  = (__half2*)(ws + 1145152);   // 1145152 .. 1177920 (32768)

    float* out = (float*)d_out;

    fused_prep_kernel<<<K1_GRID, 256, 0, stream>>>(
        cats, nums, tgt_ids, cat_emb, Wnum, bnum, Wq, Wk, Wv, Wo,
        Wpool, bpool, seq_emb, Wmlp,
        q1_W1, q1_W2, q2_W1, q2_W2, q1_Wp, q2_Wp,
        p, fused, M, seq_h2, Wmlp_h2, W12_1, W12_2, Wp1_h2, Wp2_h2);

    score_mlp_kernel<<<B_ / RM, 512, 0, stream>>>(
        seqs, (const __half*)seq_h2, seq_emb, p, M, bo, fused,
        (const __half*)Wmlp_h2, bmlp,
        W12_1, q1_b1, q1_b2, (const __half*)Wp1_h2, q1_bp,
        W12_2, q2_b1, q2_b2, (const __half*)Wp2_h2, q2_bp,
        Wout, bout, out);
}